// Round 1
// baseline (363.710 us; speedup 1.0000x reference)
//
#include <hip/hip_runtime.h>

#define D 128
#define NNODE 10000
#define LN_EPS 1e-5f

// Kernel 1: per-edge message + atomic scatter-add into agg[NNODE][3][D]
__global__ __launch_bounds__(256) void mpnn_scatter(
    const int* __restrict__ edge_index,   // [E,2]
    const float* __restrict__ vec,        // [E,3,D]
    const float* __restrict__ pv1,        // [E,D] (slice [0] of [N_V,E,D])
    const float* __restrict__ pv2,        // [E,D]
    const float* __restrict__ edge_vec,   // [E,3]
    float* __restrict__ agg,              // [NNODE,3,D]
    int E)
{
    int e = blockIdx.x * 2 + (threadIdx.x >> 7);
    int d = threadIdx.x & (D - 1);
    if (e >= E) return;
    int tgt = edge_index[e * 2 + 1];
    float p1 = pv1[(long long)e * D + d];
    float p2 = pv2[(long long)e * D + d];
#pragma unroll
    for (int c = 0; c < 3; ++c) {
        float v  = vec[((long long)e * 3 + c) * D + d];
        float ev = edge_vec[e * 3 + c];
        atomicAdd(&agg[((long long)tgt * 3 + c) * D + d], fmaf(v, p1, p2 * ev));
    }
}

// Kernel 2: gather by source index + LayerNorm(D) + write n_copy output copies
__global__ __launch_bounds__(256) void mpnn_gather_ln(
    const int* __restrict__ edge_index,   // [E,2]
    const float* __restrict__ agg,        // [NNODE,3,D]
    const float* __restrict__ gamma,      // [D]
    const float* __restrict__ beta,       // [D]
    float* __restrict__ out,              // [n_copy,E,3,D]
    long long copy_stride,                // E*3*D
    int n_copy,
    int nrows)                            // E*3
{
    int row  = blockIdx.x * 4 + (threadIdx.x >> 6);  // row = e*3 + c
    int lane = threadIdx.x & 63;
    if (row >= nrows) return;
    int e = row / 3;
    int c = row - e * 3;
    int src = edge_index[e * 2];

    const float* p = agg + ((long long)src * 3 + c) * D;
    float2 x = *(const float2*)(p + lane * 2);

    // two-pass mean / variance across 64 lanes (2 elems each)
    float s = x.x + x.y;
#pragma unroll
    for (int off = 32; off > 0; off >>= 1) s += __shfl_xor(s, off);
    float mu = s * (1.0f / (float)D);

    float dx = x.x - mu, dy = x.y - mu;
    float sq = dx * dx + dy * dy;
#pragma unroll
    for (int off = 32; off > 0; off >>= 1) sq += __shfl_xor(sq, off);
    float rstd = rsqrtf(sq * (1.0f / (float)D) + LN_EPS);

    float g0 = gamma[2 * lane], g1 = gamma[2 * lane + 1];
    float b0 = beta[2 * lane],  b1 = beta[2 * lane + 1];
    float2 y;
    y.x = fmaf(dx * rstd, g0, b0);
    y.y = fmaf(dy * rstd, g1, b1);

    long long o = (long long)row * D + lane * 2;
#pragma unroll 2
    for (int k = 0; k < n_copy; ++k)
        *(float2*)(out + (long long)k * copy_stride + o) = y;
}

extern "C" void kernel_launch(void* const* d_in, const int* in_sizes, int n_in,
                              void* d_out, int out_size, void* d_ws, size_t ws_size,
                              hipStream_t stream) {
    const int*   edge_index = (const int*)d_in[0];
    const float* vec        = (const float*)d_in[1];
    const float* pv1        = (const float*)d_in[2];   // use slice [0]
    const float* pv2        = (const float*)d_in[3];   // use slice [0]
    const float* edge_vec   = (const float*)d_in[4];
    const float* gamma      = (const float*)d_in[5];
    const float* beta       = (const float*)d_in[6];
    float* out = (float*)d_out;

    int E = in_sizes[4] / 3;                 // edge_vec is [E,3]
    long long copy_stride = (long long)E * 3 * D;
    int n_copy = (int)((long long)out_size / copy_stride);  // N_V = 2
    size_t agg_bytes = (size_t)NNODE * 3 * D * sizeof(float);

    float* agg;
    bool use_ws = (ws_size >= agg_bytes);
    if (use_ws) {
        agg = (float*)d_ws;
    } else {
        // scratch at the tail of d_out (inside the last copy's region);
        // kernel 2 then writes only copy 0, and we d2d-copy it to the rest.
        agg = out + (long long)out_size - (long long)(agg_bytes / sizeof(float));
    }

    hipMemsetAsync(agg, 0, agg_bytes, stream);

    mpnn_scatter<<<(E + 1) / 2, 256, 0, stream>>>(
        edge_index, vec, pv1, pv2, edge_vec, agg, E);

    int nrows = E * 3;
    int blocks = (nrows + 3) / 4;
    if (use_ws) {
        mpnn_gather_ln<<<blocks, 256, 0, stream>>>(
            edge_index, agg, gamma, beta, out, copy_stride, n_copy, nrows);
    } else {
        mpnn_gather_ln<<<blocks, 256, 0, stream>>>(
            edge_index, agg, gamma, beta, out, copy_stride, 1, nrows);
        for (int k = 1; k < n_copy; ++k)
            hipMemcpyAsync(out + (long long)k * copy_stride, out,
                           copy_stride * sizeof(float),
                           hipMemcpyDeviceToDevice, stream);
    }
}